// Round 5
// baseline (866.507 us; speedup 1.0000x reference)
//
#include <hip/hip_runtime.h>
#include <math.h>

#define BB   2
#define SS   2048
#define HH   8
#define DD   64
#define HIDD 512
#define NT   (BB * SS)

// ---------------------------------------------------------------------------
// All GEMMs use v_mfma_f32_16x16x32_f16 with the HW-verified layout bundle
// (validated by round-4 pass, absmax 4.9e-4):
//   A-frag: lane l supplies A[m = l&15][k = (l>>4)*8 + i]
//   B-frag: lane l supplies B[k = (l>>4)*8 + i][n = l&15]
//   D:      lane l holds   D[m = (l>>4)*4 + r][n = l&15]
// f16x3: x = hi + lo; A*B ~= Ah*Bh + Ah*Bl + Al*Bh (error ~2^-22 rel).
// Operands are SWAPPED per-kernel so that both frags are contiguous 16B
// half8 loads straight from global (no LDS, no barriers anywhere).
// ---------------------------------------------------------------------------
typedef _Float16 half8   __attribute__((ext_vector_type(8)));
typedef _Float16 half4_t __attribute__((ext_vector_type(4)));
typedef float    f32x4   __attribute__((ext_vector_type(4)));

__device__ __forceinline__ f32x4 mfma16(half8 a, half8 b, f32x4 c) {
    return __builtin_amdgcn_mfma_f32_16x16x32_f16(a, b, c, 0, 0, 0);
}

// ---------------------------------------------------------------------------
// Generic f32 -> (f16 hi, f16 lo) split, vectorized. n4 = n/4.
// ---------------------------------------------------------------------------
__global__ __launch_bounds__(256) void split_kernel(const float* __restrict__ src,
                                                    _Float16* __restrict__ dh,
                                                    _Float16* __restrict__ dl,
                                                    int n4) {
    for (int i = blockIdx.x * 256 + threadIdx.x; i < n4; i += gridDim.x * 256) {
        float4 v = ((const float4*)src)[i];
        half4_t h, l;
        h[0] = (_Float16)v.x; l[0] = (_Float16)(v.x - (float)h[0]);
        h[1] = (_Float16)v.y; l[1] = (_Float16)(v.y - (float)h[1]);
        h[2] = (_Float16)v.z; l[2] = (_Float16)(v.z - (float)h[2]);
        h[3] = (_Float16)v.w; l[3] = (_Float16)(v.w - (float)h[3]);
        ((half4_t*)dh)[i] = h;
        ((half4_t*)dl)[i] = l;
    }
}

// ---------------------------------------------------------------------------
// Projection: Y = scale*(X @ W^T + bias).  All operands pre-split f16 h/l.
// Swapped: A = W (m = out-col), B = X (n = row).  No LDS, no barriers.
// Block: 256 thr = 4 waves; wave w owns rows row0+w*16..+15, cols col0..+63.
//   OMODE 0: f16-pair head-split write [B,H,S,D]          (Q, K)
//   OMODE 1: f16-pair transposed write [B,H,D,S]          (V)
//   OMODE 2: f32 merged write [NT, HID]                   (final out)
// ---------------------------------------------------------------------------
template <int OMODE>
__global__ __launch_bounds__(256) void proj_f16(
    const _Float16* __restrict__ Xh, const _Float16* __restrict__ Xl,
    const _Float16* __restrict__ Wh, const _Float16* __restrict__ Wl,
    const float* __restrict__ bias, _Float16* __restrict__ Yh,
    _Float16* __restrict__ Yl, float* __restrict__ Yf, float scale) {
    const int tid = threadIdx.x;
    const int w = tid >> 6, l = tid & 63, lm = l & 15, lg = l >> 4;
    const int row  = blockIdx.x * 64 + w * 16 + lm;   // B n-index
    const int col0 = blockIdx.y * 64;

    const _Float16* xh = Xh + (size_t)row * HIDD;
    const _Float16* xl = Xl + (size_t)row * HIDD;

    f32x4 acc[4];
#pragma unroll
    for (int mt = 0; mt < 4; ++mt) acc[mt] = f32x4{0.f, 0.f, 0.f, 0.f};

    for (int kk = 0; kk < HIDD; kk += 32) {
        half8 bhv = *(const half8*)&xh[kk + lg * 8];
        half8 blv = *(const half8*)&xl[kk + lg * 8];
#pragma unroll
        for (int mt = 0; mt < 4; ++mt) {
            const size_t woff = (size_t)(col0 + mt * 16 + lm) * HIDD + kk + lg * 8;
            half8 ah = *(const half8*)&Wh[woff];
            half8 al = *(const half8*)&Wl[woff];
            acc[mt] = mfma16(ah, bhv, acc[mt]);
            acc[mt] = mfma16(ah, blv, acc[mt]);
            acc[mt] = mfma16(al, bhv, acc[mt]);
        }
    }

    const int b = row >> 11, s = row & (SS - 1);
    const int hcol = col0 >> 6;
#pragma unroll
    for (int mt = 0; mt < 4; ++mt) {
        const int d0 = mt * 16 + lg * 4;  // out-col within 64 (m-dim)
        float4 bv = *(const float4*)&bias[col0 + d0];
        float vals[4];
#pragma unroll
        for (int r = 0; r < 4; ++r) vals[r] = (acc[mt][r] + ((const float*)&bv)[r]) * scale;

        if constexpr (OMODE == 2) {
            float4 o = {vals[0], vals[1], vals[2], vals[3]};
            *(float4*)&Yf[(size_t)row * HIDD + col0 + d0] = o;
        } else {
            half4_t hv, lv;
#pragma unroll
            for (int r = 0; r < 4; ++r) {
                hv[r] = (_Float16)vals[r];
                lv[r] = (_Float16)(vals[r] - (float)hv[r]);
            }
            if constexpr (OMODE == 0) {
                const size_t dst = (((size_t)b * HH + hcol) * SS + s) * DD + d0;
                *(half4_t*)&Yh[dst] = hv;
                *(half4_t*)&Yl[dst] = lv;
            } else {  // OMODE 1: [B,H,D,S] transposed, scalar stores
#pragma unroll
                for (int r = 0; r < 4; ++r) {
                    const size_t dst = (((size_t)b * HH + hcol) * DD + d0 + r) * SS + s;
                    Yh[dst] = hv[r];
                    Yl[dst] = lv[r];
                }
            }
        }
    }
}

// ---------------------------------------------------------------------------
// Scores: raw masked scores -> attn (f32), online (m,l) -> stats.
// Swapped QK^T: A = K (m = kpos), B = Q (n = q).  Lane owns ONE q row,
// 4 consecutive kpos per kt -> float4 attn stores, int4 mask loads.
// Scale 1/8 pre-folded into Q.  No LDS, no barriers.
// ---------------------------------------------------------------------------
__global__ __launch_bounds__(256) void scores_f16(
    const _Float16* __restrict__ qph, const _Float16* __restrict__ qpl,
    const _Float16* __restrict__ kph, const _Float16* __restrict__ kpl,
    const int* __restrict__ mask, float* __restrict__ attn,
    float* __restrict__ mstat, float* __restrict__ lstat) {
    const int tid = threadIdx.x;
    const int w = tid >> 6, l = tid & 63, lm = l & 15, lg = l >> 4;
    const int bh = blockIdx.y, b = bh >> 3;
    const int q = blockIdx.x * 64 + w * 16 + lm;

    const size_t qoff = ((size_t)bh * SS + q) * DD;
    half8 qfh[2], qfl[2];
#pragma unroll
    for (int ks = 0; ks < 2; ++ks) {
        qfh[ks] = *(const half8*)&qph[qoff + ks * 32 + lg * 8];
        qfl[ks] = *(const half8*)&qpl[qoff + ks * 32 + lg * 8];
    }

    const int* mrow = mask + ((size_t)b * SS + q) * SS;
    float* arow = attn + ((size_t)bh * SS + q) * SS;
    const _Float16* kb_h = kph + (size_t)bh * SS * DD;
    const _Float16* kb_l = kpl + (size_t)bh * SS * DD;

    float m = -INFINITY, lsum = 0.f;

    for (int k0 = 0; k0 < SS; k0 += 64) {
        float sv[16];
#pragma unroll
        for (int kt = 0; kt < 4; ++kt) {
            const size_t koff = (size_t)(k0 + kt * 16 + lm) * DD;
            f32x4 sacc = f32x4{0.f, 0.f, 0.f, 0.f};
#pragma unroll
            for (int ks = 0; ks < 2; ++ks) {
                half8 ah = *(const half8*)&kb_h[koff + ks * 32 + lg * 8];
                half8 al = *(const half8*)&kb_l[koff + ks * 32 + lg * 8];
                sacc = mfma16(ah, qfh[ks], sacc);
                sacc = mfma16(ah, qfl[ks], sacc);
                sacc = mfma16(al, qfh[ks], sacc);
            }
            int4 mk = *(const int4*)&mrow[k0 + kt * 16 + lg * 4];
            float4 s4;
            s4.x = mk.x ? sacc[0] : -1e10f;
            s4.y = mk.y ? sacc[1] : -1e10f;
            s4.z = mk.z ? sacc[2] : -1e10f;
            s4.w = mk.w ? sacc[3] : -1e10f;
            *(float4*)&arow[k0 + kt * 16 + lg * 4] = s4;
            sv[kt * 4 + 0] = s4.x; sv[kt * 4 + 1] = s4.y;
            sv[kt * 4 + 2] = s4.z; sv[kt * 4 + 3] = s4.w;
        }
        float tmax = sv[0];
#pragma unroll
        for (int i = 1; i < 16; ++i) tmax = fmaxf(tmax, sv[i]);
        tmax = fmaxf(tmax, __shfl_xor(tmax, 16, 64));
        tmax = fmaxf(tmax, __shfl_xor(tmax, 32, 64));
        const float mn = fmaxf(m, tmax);
        float ps = 0.f;
#pragma unroll
        for (int i = 0; i < 16; ++i) ps += __expf(sv[i] - mn);
        ps += __shfl_xor(ps, 16, 64);
        ps += __shfl_xor(ps, 32, 64);
        lsum = lsum * __expf(m - mn) + ps;
        m = mn;
    }

    if (lg == 0) {
        mstat[(size_t)bh * SS + q] = m;
        lstat[(size_t)bh * SS + q] = lsum;
    }
}

// ---------------------------------------------------------------------------
// PV: p = exp(s-m)/l, overwrite attn with p, x = P @ V, write x split f16.
// Swapped: A = V^T (m = dv) from vt [B,H,D,S], B = P (n = q) built in-lane
// from contiguous attn float4 reads.  No LDS, no barriers.
// ---------------------------------------------------------------------------
__global__ __launch_bounds__(256) void pv_f16(
    const _Float16* __restrict__ vth, const _Float16* __restrict__ vtl,
    float* __restrict__ attn, const float* __restrict__ mstat,
    const float* __restrict__ lstat, _Float16* __restrict__ xh,
    _Float16* __restrict__ xl) {
    const int tid = threadIdx.x;
    const int w = tid >> 6, l = tid & 63, lm = l & 15, lg = l >> 4;
    const int bh = blockIdx.y, b = bh >> 3, h = bh & 7;
    const int q = blockIdx.x * 64 + w * 16 + lm;

    const float m  = mstat[(size_t)bh * SS + q];
    const float rl = 1.0f / lstat[(size_t)bh * SS + q];
    float* arow = attn + ((size_t)bh * SS + q) * SS;
    const _Float16* vb_h = vth + (size_t)bh * DD * SS;
    const _Float16* vb_l = vtl + (size_t)bh * DD * SS;

    f32x4 acc[4];
#pragma unroll
    for (int nt = 0; nt < 4; ++nt) acc[nt] = f32x4{0.f, 0.f, 0.f, 0.f};

    for (int k0 = 0; k0 < SS; k0 += 64) {
        half8 pfh[2], pfl[2];
#pragma unroll
        for (int ks = 0; ks < 2; ++ks) {
            const int cb = k0 + ks * 32 + lg * 8;
            float4 s0 = *(const float4*)&arow[cb];
            float4 s1 = *(const float4*)&arow[cb + 4];
            float p[8];
            p[0] = __expf(s0.x - m) * rl; p[1] = __expf(s0.y - m) * rl;
            p[2] = __expf(s0.z - m) * rl; p[3] = __expf(s0.w - m) * rl;
            p[4] = __expf(s1.x - m) * rl; p[5] = __expf(s1.y - m) * rl;
            p[6] = __expf(s1.z - m) * rl; p[7] = __expf(s1.w - m) * rl;
            float4 o0 = {p[0], p[1], p[2], p[3]};
            float4 o1 = {p[4], p[5], p[6], p[7]};
            *(float4*)&arow[cb]     = o0;
            *(float4*)&arow[cb + 4] = o1;
            half8 ph, pl;
#pragma unroll
            for (int i = 0; i < 8; ++i) {
                ph[i] = (_Float16)p[i];
                pl[i] = (_Float16)(p[i] - (float)ph[i]);
            }
            pfh[ks] = ph; pfl[ks] = pl;
        }
#pragma unroll
        for (int nt = 0; nt < 4; ++nt) {
#pragma unroll
            for (int ks = 0; ks < 2; ++ks) {
                const size_t voff = (size_t)(nt * 16 + lm) * SS + k0 + ks * 32 + lg * 8;
                half8 vh = *(const half8*)&vb_h[voff];
                half8 vl = *(const half8*)&vb_l[voff];
                acc[nt] = mfma16(vh, pfh[ks], acc[nt]);
                acc[nt] = mfma16(vh, pfl[ks], acc[nt]);
                acc[nt] = mfma16(vl, pfh[ks], acc[nt]);
            }
        }
    }

#pragma unroll
    for (int nt = 0; nt < 4; ++nt) {
        half4_t hv, lv;
#pragma unroll
        for (int r = 0; r < 4; ++r) {
            const float val = acc[nt][r];
            hv[r] = (_Float16)val;
            lv[r] = (_Float16)(val - (float)hv[r]);
        }
        const size_t dst = ((size_t)b * SS + q) * HIDD + h * DD + nt * 16 + lg * 4;
        *(half4_t*)&xh[dst] = hv;
        *(half4_t*)&xl[dst] = lv;
    }
}

// ---------------------------------------------------------------------------
extern "C" void kernel_launch(void* const* d_in, const int* in_sizes, int n_in,
                              void* d_out, int out_size, void* d_ws,
                              size_t ws_size, hipStream_t stream) {
    const float* q  = (const float*)d_in[0];
    const float* k  = (const float*)d_in[1];
    const float* v  = (const float*)d_in[2];
    const int* mask = (const int*)d_in[3];
    const float* Wq = (const float*)d_in[4];
    const float* bq = (const float*)d_in[5];
    const float* Wk = (const float*)d_in[6];
    const float* bk = (const float*)d_in[7];
    const float* Wv = (const float*)d_in[8];
    const float* bv = (const float*)d_in[9];
    const float* Wo = (const float*)d_in[10];
    const float* bo = (const float*)d_in[11];

    float* out  = (float*)d_out;                    // [B, S, HID]
    float* attn = out + (size_t)BB * SS * HIDD;     // [B, H, S, S]

    const size_t NE = (size_t)NT * HIDD;  // 2M elements
    const size_t WE = (size_t)HIDD * HIDD;

    _Float16* p = (_Float16*)d_ws;
    _Float16 *qsh = p, *qsl = qsh + NE, *ksh = qsl + NE, *ksl = ksh + NE;
    _Float16 *vsh = ksl + NE, *vsl = vsh + NE;
    p = vsl + NE;
    _Float16 *wqh = p, *wql = wqh + WE, *wkh = wql + WE, *wkl = wkh + WE;
    _Float16 *wvh = wkl + WE, *wvl = wvh + WE, *woh = wvl + WE, *wol = woh + WE;
    p = wol + WE;
    _Float16 *qph = p, *qpl = qph + NE, *kph = qpl + NE, *kpl = kph + NE;
    _Float16 *vth = kpl + NE, *vtl = vth + NE;   // [B,H,D,S]
    _Float16 *xh = vtl + NE, *xl = xh + NE;      // [B,S,HID]
    p = xl + NE;
    float* mstat = (float*)p;                    // [B,H,S]
    float* lstat = mstat + (size_t)BB * HH * SS;

    // ---- pre-split everything to f16 hi/lo ----
    const int n4i = (int)(NE / 4), n4w = (int)(WE / 4);
    split_kernel<<<2048, 256, 0, stream>>>(q, qsh, qsl, n4i);
    split_kernel<<<2048, 256, 0, stream>>>(k, ksh, ksl, n4i);
    split_kernel<<<2048, 256, 0, stream>>>(v, vsh, vsl, n4i);
    split_kernel<<<256, 256, 0, stream>>>(Wq, wqh, wql, n4w);
    split_kernel<<<256, 256, 0, stream>>>(Wk, wkh, wkl, n4w);
    split_kernel<<<256, 256, 0, stream>>>(Wv, wvh, wvl, n4w);
    split_kernel<<<256, 256, 0, stream>>>(Wo, woh, wol, n4w);

    // ---- projections (scale 1/8 folded into Q) ----
    dim3 gproj(NT / 64, HIDD / 64);
    proj_f16<0><<<gproj, 256, 0, stream>>>(qsh, qsl, wqh, wql, bq, qph, qpl,
                                           nullptr, 0.125f);
    proj_f16<0><<<gproj, 256, 0, stream>>>(ksh, ksl, wkh, wkl, bk, kph, kpl,
                                           nullptr, 1.0f);
    proj_f16<1><<<gproj, 256, 0, stream>>>(vsh, vsl, wvh, wvl, bv, vth, vtl,
                                           nullptr, 1.0f);

    // ---- attention ----
    dim3 gattn(SS / 64, BB * HH);
    scores_f16<<<gattn, 256, 0, stream>>>(qph, qpl, kph, kpl, mask, attn,
                                          mstat, lstat);
    pv_f16<<<gattn, 256, 0, stream>>>(vth, vtl, attn, mstat, lstat, xh, xl);

    // ---- output projection (f32 out) ----
    proj_f16<2><<<gproj, 256, 0, stream>>>(xh, xl, woh, wol, bo, nullptr,
                                           nullptr, out, 1.0f);
}